// Round 1
// baseline (416.197 us; speedup 1.0000x reference)
//
#include <hip/hip_runtime.h>

#define D 128
#define PCHUNK 4096
#define SCAP 8192

typedef short bf16x8 __attribute__((ext_vector_type(8)));
typedef float f32x4 __attribute__((ext_vector_type(4)));

__device__ __forceinline__ ushort f2b(float f){
  unsigned u = __builtin_bit_cast(unsigned, f);
  u += 0x7fffu + ((u >> 16) & 1u);          // round-to-nearest-even
  return (ushort)(u >> 16);
}
__device__ __forceinline__ float b2f(ushort h){
  unsigned u = ((unsigned)h) << 16;
  return __builtin_bit_cast(float, u);
}

// ---------------- P0: coarse bucket histogram (bucket = dst>>8) ----------------
__global__ __launch_bounds__(256) void k_p0(const int* __restrict__ dst,
                                            int* __restrict__ bcnt, int E){
  __shared__ int h[512];
  for (int u=threadIdx.x; u<512; u+=256) h[u]=0;
  __syncthreads();
  for (long long i=(long long)blockIdx.x*256+threadIdx.x; i<E; i+=(long long)gridDim.x*256)
    atomicAdd(&h[dst[i]>>8], 1);
  __syncthreads();
  for (int u=threadIdx.x; u<512; u+=256) if (h[u]) atomicAdd(&bcnt[u], h[u]);
}

// ---------------- P1: scan buckets -> base & cursor ----------------
__global__ void k_bscan(const int* __restrict__ bcnt, int* __restrict__ bbase,
                        int* __restrict__ bcur, int nb, int E){
  __shared__ int sh[1024];
  int t = threadIdx.x;
  int v = (t<nb) ? bcnt[t] : 0;
  sh[t]=v; __syncthreads();
  for (int off=1; off<1024; off<<=1){
    int add = (t>=off)?sh[t-off]:0;
    __syncthreads();
    sh[t]+=add;
    __syncthreads();
  }
  if (t<nb){ int e=sh[t]-v; bbase[t]=e; bcur[t]=e; }
  if (t==nb) bbase[t]=E;
}

// ---------------- P2: LDS-binned partition of (src,dst) into buckets ----------------
__global__ __launch_bounds__(256) void k_part(const int* __restrict__ src,
        const int* __restrict__ dst, int* __restrict__ bcur,
        int2* __restrict__ pairs, int E){
  __shared__ int hist[512], offA[512], offB[512], gbase[512];
  __shared__ int sS[PCHUNK], sD[PCHUNK];
  const int t = threadIdx.x;
  const int base = blockIdx.x * PCHUNK;
  const int cnt = min(PCHUNK, E - base);
  for (int u=t; u<512; u+=256) hist[u]=0;
  __syncthreads();
  int rs[16], rd[16];
  #pragma unroll
  for (int j=0;j<16;j++){
    int li = j*256 + t;
    if (li < cnt){
      rs[j]=src[base+li]; rd[j]=dst[base+li];
      atomicAdd(&hist[rd[j]>>8],1);
    } else { rs[j]=0; rd[j]=-1; }
  }
  __syncthreads();
  // inclusive scan of hist (512 entries, double-buffer Hillis-Steele)
  int *cur=offA, *nxt=offB;
  for (int u=t; u<512; u+=256) cur[u]=hist[u];
  __syncthreads();
  for (int off=1; off<512; off<<=1){
    for (int u=t; u<512; u+=256) nxt[u] = cur[u] + ((u>=off)?cur[u-off]:0);
    __syncthreads();
    int* tmp=cur; cur=nxt; nxt=tmp;
  }
  // nxt = per-bucket cursor (exclusive base)
  for (int u=t; u<512; u+=256) nxt[u] = cur[u]-hist[u];
  __syncthreads();
  // place into LDS bins
  #pragma unroll
  for (int j=0;j<16;j++){
    if (j*256+t < cnt){
      int b = rd[j]>>8;
      int p = atomicAdd(&nxt[b],1);
      sS[p]=rs[j]; sD[p]=rd[j];
    }
  }
  __syncthreads();
  // claim global space per bucket
  for (int u=t; u<512; u+=256){
    int c = hist[u];
    if (c>0) gbase[u] = atomicAdd(&bcur[u], c);
  }
  __syncthreads();
  // flush (runs per bucket are contiguous -> coalesced)
  #pragma unroll
  for (int j=0;j<16;j++){
    int idx = j*256+t;
    if (idx<cnt){
      int d = sD[idx]; int b = d>>8;
      int gpos = gbase[b] + (idx - (cur[b]-hist[b]));
      pairs[gpos] = make_int2(sS[idx], d);
    }
  }
}

// ---------------- P3: per-bucket exact counting sort -> slots + offs ----------------
__global__ __launch_bounds__(256) void k_sortb(const int2* __restrict__ pairs,
        const int* __restrict__ bbase, int* __restrict__ offs,
        int* __restrict__ slots, int N, int NB){
  __shared__ int nh[256], nc[256], sc[256];
  __shared__ int stage[SCAP];
  const int b = blockIdx.x, t = threadIdx.x;
  const int base = bbase[b];
  const int cnt  = bbase[b+1] - base;
  nh[t]=0; __syncthreads();
  for (int i=t;i<cnt;i+=256) atomicAdd(&nh[pairs[base+i].y & 255],1);
  __syncthreads();
  int v = nh[t];
  sc[t]=v; __syncthreads();
  for (int off=1; off<256; off<<=1){
    int add = (t>=off)?sc[t-off]:0;
    __syncthreads();
    sc[t]+=add;
    __syncthreads();
  }
  int excl = sc[t]-v;
  nc[t]=excl;
  int node = (b<<8)+t;
  if (node<N) offs[node]=base+excl;
  if (b==NB-1 && t==0) offs[N]=bbase[NB];
  __syncthreads();
  if (cnt<=SCAP){
    for (int i=t;i<cnt;i+=256){
      int2 p = pairs[base+i];
      int pos = atomicAdd(&nc[p.y & 255],1);
      stage[pos]=p.x;
    }
    __syncthreads();
    for (int i=t;i<cnt;i+=256) slots[base+i]=stage[i];
  } else {
    for (int i=t;i<cnt;i+=256){
      int2 p = pairs[base+i];
      int pos = atomicAdd(&nc[p.y & 255],1);
      slots[base+pos]=p.x;
    }
  }
}

// ---------------- f32 -> bf16 cast ----------------
__global__ __launch_bounds__(256) void k_xcast(const float* __restrict__ x,
                                               ushort* __restrict__ xb, long long n4){
  long long i = (long long)blockIdx.x*256 + threadIdx.x;
  const long long stride = (long long)gridDim.x*256;
  for (; i < n4; i += stride){
    float4 v = reinterpret_cast<const float4*>(x)[i];
    ushort4 o;
    o.x = f2b(v.x); o.y = f2b(v.y); o.z = f2b(v.z); o.w = f2b(v.w);
    reinterpret_cast<ushort4*>(xb)[i] = o;
  }
}

// ---------------- weight transpose+cast: Wb[c*K + k0 + k] = bf16(W[k][c]) ----------------
__global__ void k_wt(const float* __restrict__ W, ushort* __restrict__ Wb, int K, int k0){
  int idx = blockIdx.x*256 + threadIdx.x;   // 0..16383
  int k = idx >> 7, c = idx & 127;
  Wb[(size_t)c*K + k0 + k] = f2b(W[idx]);
}

// ---------------- gather-mean (bf16 in/out): 64 threads per node ----------------
__global__ __launch_bounds__(256) void k_gatherb(const ushort* __restrict__ Xb,
        const int* __restrict__ slots, const int* __restrict__ offs,
        ushort* __restrict__ meanb, int N){
  int node = blockIdx.x*4 + (threadIdx.x >> 6);
  int c = threadIdx.x & 63;
  if (node >= N) return;
  int beg = offs[node], end = offs[node+1];
  float sx0=0,sy0=0,sx1=0,sy1=0,sx2=0,sy2=0,sx3=0,sy3=0;
  int j = beg;
  for (; j + 4 <= end; j += 4){
    int n0=slots[j], n1=slots[j+1], n2=slots[j+2], n3=slots[j+3];
    unsigned u0 = *reinterpret_cast<const unsigned*>(&Xb[(size_t)n0*D + c*2]);
    unsigned u1 = *reinterpret_cast<const unsigned*>(&Xb[(size_t)n1*D + c*2]);
    unsigned u2 = *reinterpret_cast<const unsigned*>(&Xb[(size_t)n2*D + c*2]);
    unsigned u3 = *reinterpret_cast<const unsigned*>(&Xb[(size_t)n3*D + c*2]);
    sx0 += b2f((ushort)u0); sy0 += b2f((ushort)(u0>>16));
    sx1 += b2f((ushort)u1); sy1 += b2f((ushort)(u1>>16));
    sx2 += b2f((ushort)u2); sy2 += b2f((ushort)(u2>>16));
    sx3 += b2f((ushort)u3); sy3 += b2f((ushort)(u3>>16));
  }
  for (; j < end; ++j){
    unsigned u = *reinterpret_cast<const unsigned*>(&Xb[(size_t)slots[j]*D + c*2]);
    sx0 += b2f((ushort)u); sy0 += b2f((ushort)(u>>16));
  }
  float deg = (float)(end - beg);
  float rc = deg > 0.f ? 1.0f/deg : 0.f;
  unsigned o = (unsigned)f2b((sx0+sx1+sx2+sx3)*rc)
             | ((unsigned)f2b((sy0+sy1+sy2+sy3)*rc) << 16);
  *reinterpret_cast<unsigned*>(&meanb[(size_t)node*D + c*2]) = o;
}

// ---------------- barrier-free, LDS-free MFMA GEMM ----------------
// C = [A0 | A1] @ Wb^T + bias, bf16 out, f32 BN stats.
// KSTEP = number of 32-wide K-steps (8 -> K=256 with A0/A1 halves; 4 -> K=128, A0 only).
// Fragments (A rows + W cols) are loaded straight from global memory, double-buffered
// in registers. No __shared__ staging and no __syncthreads in the main loop, so waves
// pipeline independently; one accumulator (64 AGPRs) keeps combined regs ~2 waves/SIMD.
template<int KSTEP>
__global__ __launch_bounds__(256) void k_gemm(
    const ushort* __restrict__ A0, const ushort* __restrict__ A1,
    const ushort* __restrict__ Wb, const float* __restrict__ bias,
    ushort* __restrict__ C, float* __restrict__ gS, float* __restrict__ gQ,
    int N)
{
  constexpr int K = KSTEP * 32;
  __shared__ float shS[128], shQ[128];
  const int tid = threadIdx.x;
  if (tid < 128){ shS[tid]=0.f; shQ[tid]=0.f; }
  __syncthreads();

  const int lane = tid & 63, wid = tid >> 6;
  const int wr = wid >> 1, wc = wid & 1;
  const int lr = lane & 15, kq = lane >> 4;
  const int row0 = blockIdx.x * 128;

  // A-fragment row byte offsets (row clamped so OOB lanes read a valid row;
  // their results are discarded by the row<N guard in the epilogue)
  size_t rowoff[4];
  #pragma unroll
  for (int m=0;m<4;m++){
    int r = row0 + 64*wr + 16*m + lr;
    if (r >= N) r = N-1;
    rowoff[m] = (size_t)r * D;
  }
  // W-fragment row pointers (Wb is [col][K], col = 64*wc + 16*n + lr)
  const ushort* wp[4];
  #pragma unroll
  for (int n=0;n<4;n++) wp[n] = Wb + (size_t)(64*wc + 16*n + lr) * K + kq*8;

  f32x4 acc[4][4];
  #pragma unroll
  for (int m=0;m<4;m++)
    #pragma unroll
    for (int n=0;n<4;n++) acc[m][n] = (f32x4){0.f,0.f,0.f,0.f};

  int4 aC[4], wC[4], aN[4], wN[4];
  // prime t = 0
  #pragma unroll
  for (int m=0;m<4;m++) aC[m] = *reinterpret_cast<const int4*>(A0 + rowoff[m] + kq*8);
  #pragma unroll
  for (int n=0;n<4;n++) wC[n] = *reinterpret_cast<const int4*>(wp[n]);

  #pragma unroll
  for (int t=0; t<KSTEP; ++t){
    if (t+1 < KSTEP){
      const int tn = t + 1;
      const ushort* ab = (KSTEP == 8 && tn >= 4) ? A1 : A0;
      const int ka = (tn & 3) * 32 + kq*8;
      #pragma unroll
      for (int m=0;m<4;m++) aN[m] = *reinterpret_cast<const int4*>(ab + rowoff[m] + ka);
      #pragma unroll
      for (int n=0;n<4;n++) wN[n] = *reinterpret_cast<const int4*>(wp[n] + tn*32);
    }
    #pragma unroll
    for (int m=0;m<4;m++){
      bf16x8 af = __builtin_bit_cast(bf16x8, aC[m]);
      #pragma unroll
      for (int n=0;n<4;n++)
        acc[m][n] = __builtin_amdgcn_mfma_f32_16x16x32_bf16(
            af, __builtin_bit_cast(bf16x8, wC[n]), acc[m][n], 0, 0, 0);
    }
    if (t+1 < KSTEP){
      #pragma unroll
      for (int m=0;m<4;m++){ aC[m] = aN[m]; wC[m] = wN[m]; }
    }
  }

  // epilogue: bias + bf16 store + BN partial stats
  float bv[4];
  #pragma unroll
  for (int n=0;n<4;n++) bv[n] = bias[64*wc + 16*n + lr];
  float bs[4]={0,0,0,0}, bq[4]={0,0,0,0};
  #pragma unroll
  for (int m=0;m<4;m++){
    #pragma unroll
    for (int r=0;r<4;r++){
      int row = row0 + 64*wr + 16*m + kq*4 + r;
      if (row < N){
        #pragma unroll
        for (int n=0;n<4;n++){
          int col = 64*wc + 16*n + lr;
          float v = acc[m][n][r] + bv[n];
          C[(size_t)row*D + col] = f2b(v);
          bs[n] += v; bq[n] += v*v;
        }
      }
    }
  }
  // reduce over the 4 kq lane-groups (same output column), then LDS-accumulate
  #pragma unroll
  for (int n=0;n<4;n++){
    bs[n] += __shfl_xor(bs[n], 16); bs[n] += __shfl_xor(bs[n], 32);
    bq[n] += __shfl_xor(bq[n], 16); bq[n] += __shfl_xor(bq[n], 32);
    if (kq == 0){
      int col = 64*wc + 16*n + lr;
      atomicAdd(&shS[col], bs[n]);
      atomicAdd(&shQ[col], bq[n]);
    }
  }
  __syncthreads();
  if (tid < 128){
    unsafeAtomicAdd(&gS[tid], shS[tid]);
    unsafeAtomicAdd(&gQ[tid], shQ[tid]);
  }
}

// ---------------- BN finalize ----------------
__global__ void k_bnfin(const float* __restrict__ sum, const float* __restrict__ sq,
                        const float* __restrict__ g, const float* __restrict__ be,
                        float* __restrict__ bnA, float* __restrict__ bnB, float invN){
  int c = threadIdx.x;
  float m = sum[c]*invN;
  float v = sq[c]*invN - m*m;
  float a = g[c]*rsqrtf(fmaxf(v, 0.f) + 1e-5f);
  bnA[c] = a;
  bnB[c] = be[c] - m*a;
}

// ---------------- BN + ReLU, bf16 in -> bf16 out ----------------
__global__ __launch_bounds__(256) void k_bnrelub(const ushort* __restrict__ hpre,
      ushort* __restrict__ hb,
      const float* __restrict__ A, const float* __restrict__ Bp, long long n4){
  long long i = (long long)blockIdx.x*256 + threadIdx.x;
  const long long stride = (long long)gridDim.x*256;
  for (; i < n4; i += stride){
    int c = ((int)(i & 31)) << 2;
    float4 a = *reinterpret_cast<const float4*>(A + c);
    float4 b = *reinterpret_cast<const float4*>(Bp + c);
    ushort4 hv = reinterpret_cast<const ushort4*>(hpre)[i];
    ushort4 o;
    o.x = f2b(fmaxf(a.x*b2f(hv.x) + b.x, 0.f));
    o.y = f2b(fmaxf(a.y*b2f(hv.y) + b.y, 0.f));
    o.z = f2b(fmaxf(a.z*b2f(hv.z) + b.z, 0.f));
    o.w = f2b(fmaxf(a.w*b2f(hv.w) + b.w, 0.f));
    reinterpret_cast<ushort4*>(hb)[i] = o;
  }
}

// ---------------- final: out = relu(bn2(h2) + bn3(skip)), f32 out ----------------
__global__ __launch_bounds__(256) void k_final(const ushort* __restrict__ h2,
      const ushort* __restrict__ sk, float* __restrict__ out,
      const float* __restrict__ A2, const float* __restrict__ B2,
      const float* __restrict__ A3, const float* __restrict__ B3, long long n4){
  long long i = (long long)blockIdx.x*256 + threadIdx.x;
  const long long stride = (long long)gridDim.x*256;
  for (; i < n4; i += stride){
    int c = ((int)(i & 31)) << 2;
    float4 a2 = *reinterpret_cast<const float4*>(A2 + c);
    float4 b2 = *reinterpret_cast<const float4*>(B2 + c);
    float4 a3 = *reinterpret_cast<const float4*>(A3 + c);
    float4 b3 = *reinterpret_cast<const float4*>(B3 + c);
    ushort4 h = reinterpret_cast<const ushort4*>(h2)[i];
    ushort4 s = reinterpret_cast<const ushort4*>(sk)[i];
    float4 v;
    v.x = fmaxf(a2.x*b2f(h.x) + b2.x + a3.x*b2f(s.x) + b3.x, 0.f);
    v.y = fmaxf(a2.y*b2f(h.y) + b2.y + a3.y*b2f(s.y) + b3.y, 0.f);
    v.z = fmaxf(a2.z*b2f(h.z) + b2.z + a3.z*b2f(s.z) + b3.z, 0.f);
    v.w = fmaxf(a2.w*b2f(h.w) + b2.w + a3.w*b2f(s.w) + b3.w, 0.f);
    reinterpret_cast<float4*>(out)[i] = v;
  }
}

extern "C" void kernel_launch(void* const* d_in, const int* in_sizes, int n_in,
                              void* d_out, int out_size, void* d_ws, size_t ws_size,
                              hipStream_t stream) {
  const float* x        = (const float*)d_in[0];
  const int*   src      = (const int*)  d_in[1];
  const int*   dst      = (const int*)  d_in[2];
  const float* w_self1  = (const float*)d_in[3];
  const float* w_neigh1 = (const float*)d_in[4];
  const float* b1       = (const float*)d_in[5];
  const float* w_self2  = (const float*)d_in[6];
  const float* w_neigh2 = (const float*)d_in[7];
  const float* b2       = (const float*)d_in[8];
  const float* w_skip   = (const float*)d_in[9];
  const float* b_skip   = (const float*)d_in[10];
  const float* g1       = (const float*)d_in[11];
  const float* be1      = (const float*)d_in[12];
  const float* g2       = (const float*)d_in[13];
  const float* be2      = (const float*)d_in[14];
  const float* g3       = (const float*)d_in[15];
  const float* be3      = (const float*)d_in[16];
  (void)n_in; (void)ws_size;

  const int N = in_sizes[0] / D;
  const int E = in_sizes[1];
  const int NB = (N + 255) >> 8;            // coarse buckets (<=512 for N<=131072)
  float* out = (float*)d_out;

  // ---- workspace layout ----
  char* p = (char*)d_ws;
  const size_t nd2 = (((size_t)N * D * 2) + 255) / 256 * 256;   // bf16 [N][D]
  ushort* meanb  = (ushort*)p; p += nd2;
  ushort* h1b    = (ushort*)p; p += nd2;
  ushort* hpre_b = (ushort*)p; p += nd2;     // h1pre, then h2pre (aliased)
  ushort* skip_b = (ushort*)p; p += nd2;
  ushort* Wb1    = (ushort*)p; p += 256*128*2;
  ushort* Wb2    = (ushort*)p; p += 256*128*2;
  ushort* Wb3    = (ushort*)p; p += 128*128*2;
  int*    offs   = (int*)p;   p += (((size_t)(N+1)*4) + 255) / 256 * 256;
  int*    bcnt   = (int*)p;   p += 2304;     // 513 ints padded
  float*  st     = (float*)p; p += 1536*sizeof(float);
  int*    bbase  = (int*)p;   p += 2304;
  int*    bcur   = (int*)p;   p += 2048;
  float *sum1=st,      *sq1=st+128,  *sum2=st+256, *sq2=st+384, *sum3=st+512, *sq3=st+640;
  float *bnA1=st+768,  *bnB1=st+896, *bnA2=st+1024,*bnB2=st+1152,*bnA3=st+1280,*bnB3=st+1408;

  // scratch in d_out (dead before k_final rewrites all of d_out)
  const size_t slpad = (((size_t)E*4) + 255) / 256 * 256;
  const size_t xbpad = (((size_t)N*D*2) + 255) / 256 * 256;
  int*    slots = (int*)d_out;
  ushort* xb    = (ushort*)((char*)d_out + slpad);
  int2*   pairs = (int2*)((char*)d_out + slpad + xbpad);

  // zero bucket counters + stats (adjacent)
  hipMemsetAsync(bcnt, 0, 2304 + 1536*sizeof(float), stream);

  const long long n4 = (long long)N * D / 4;

  // --- casts / weight prep ---
  k_xcast<<<2048, 256, 0, stream>>>(x, xb, n4);
  k_wt<<<64, 256, 0, stream>>>(w_self1,  Wb1, 256, 0);
  k_wt<<<64, 256, 0, stream>>>(w_neigh1, Wb1, 256, 128);
  k_wt<<<64, 256, 0, stream>>>(w_self2,  Wb2, 256, 0);
  k_wt<<<64, 256, 0, stream>>>(w_neigh2, Wb2, 256, 128);
  k_wt<<<64, 256, 0, stream>>>(w_skip,   Wb3, 128, 0);

  // --- CSR build via 2-level counting sort ---
  k_p0<<<1024, 256, 0, stream>>>(dst, bcnt, E);
  k_bscan<<<1, 1024, 0, stream>>>(bcnt, bbase, bcur, NB, E);
  k_part<<<(E + PCHUNK - 1)/PCHUNK, 256, 0, stream>>>(src, dst, bcur, pairs, E);
  k_sortb<<<NB, 256, 0, stream>>>(pairs, bbase, offs, slots, N, NB);

  const int gablocks = (N + 3) / 4;
  const int gmblocks = (N + 127) / 128;
  const float invN = 1.0f / (float)N;

  // --- layer 1 ---
  k_gatherb<<<gablocks, 256, 0, stream>>>(xb, slots, offs, meanb, N);
  k_gemm<8><<<gmblocks, 256, 0, stream>>>(xb, meanb, Wb1, b1, hpre_b, sum1, sq1, N);
  k_bnfin<<<1, 128, 0, stream>>>(sum1, sq1, g1, be1, bnA1, bnB1, invN);
  k_bnrelub<<<4096, 256, 0, stream>>>(hpre_b, h1b, bnA1, bnB1, n4);

  // --- layer 2 aggregation ---
  k_gatherb<<<gablocks, 256, 0, stream>>>(h1b, slots, offs, meanb, N);

  // layer-2 GEMM (hpre_b reused as h2pre) + separate skip GEMM
  k_gemm<8><<<gmblocks, 256, 0, stream>>>(h1b, meanb, Wb2, b2, hpre_b, sum2, sq2, N);
  k_gemm<4><<<gmblocks, 256, 0, stream>>>(h1b, nullptr, Wb3, b_skip, skip_b, sum3, sq3, N);
  k_bnfin<<<1, 128, 0, stream>>>(sum2, sq2, g2, be2, bnA2, bnB2, invN);
  k_bnfin<<<1, 128, 0, stream>>>(sum3, sq3, g3, be3, bnA3, bnB3, invN);

  k_final<<<4096, 256, 0, stream>>>(hpre_b, skip_b, out, bnA2, bnB2, bnA3, bnB3, n4);
}